// Round 5
// baseline (534.065 us; speedup 1.0000x reference)
//
#include <hip/hip_runtime.h>
#include <math.h>

#define D 896
#define NTOK 16384
#define INV_SQRT_D 0.03340766f  // 1/sqrt(896)

typedef __bf16 bf16x8 __attribute__((ext_vector_type(8)));
typedef float f32x4 __attribute__((ext_vector_type(4)));
typedef float f32x8 __attribute__((ext_vector_type(8)));
typedef unsigned short u16x8 __attribute__((ext_vector_type(8)));

__device__ __forceinline__ float sigmoidf_(float x) {
  return 1.f / (1.f + __expf(-x));
}
__device__ __forceinline__ float b2f(unsigned short u) {
  return __uint_as_float(((unsigned int)u) << 16);
}
__device__ __forceinline__ unsigned short f2bf(float f) {
  const unsigned int u = __float_as_uint(f);
  return (unsigned short)((u + 0x7fffu + ((u >> 16) & 1u)) >> 16);
}
__device__ __forceinline__ bf16x8 ld8(const unsigned short* p) {
  return __builtin_bit_cast(bf16x8, *(const u16x8*)p);
}
__device__ __forceinline__ void gl_lds16(const void* g, void* l) {
  __builtin_amdgcn_global_load_lds(
      (const __attribute__((address_space(1))) void*)g,
      (__attribute__((address_space(3))) void*)l, 16, 0, 0);
}

// ===================== PLAN A: 256x256 8-phase bf16 GEMM =====================
// R5 change vs R4 (K-loop and skeleton UNTOUCHED — best measured config):
//   * MODE1/MODE2 epilogue rebuilt: acc -> LDS (row-major [64][276] f32,
//     conflict-free dump) -> vectorized u16x8/f32x4 global IO in 4 chunks.
//     Fixes the measured 2x write amplification (116.7MB -> 58.7MB for MODE1)
//     and cuts VMEM insts 512->64 per thread (MODE1) / 128->32 (MODE2).

// Fused f32->bf16 conversions (h, u, Wa, Wg, Wf) + logit zero, one launch.
__global__ __launch_bounds__(256) void prep_k(
    const float* __restrict__ h, const float* __restrict__ u,
    const float* __restrict__ wa, const float* __restrict__ wg,
    const float* __restrict__ wf, unsigned short* __restrict__ h_bf,
    unsigned short* __restrict__ u_bf, unsigned short* __restrict__ wa_bf,
    unsigned short* __restrict__ wg_bf, unsigned short* __restrict__ wf_bf,
    float* __restrict__ logit) {
  int b = blockIdx.x;
  const float* src;
  unsigned short* dst;
  if (b < 7168) {
    src = h; dst = h_bf;
  } else if (b < 14336) {
    b -= 7168; src = u; dst = u_bf;
  } else if (b < 14728) {
    b -= 14336; src = wa; dst = wa_bf;
  } else if (b < 15512) {
    b -= 14728; src = wg; dst = wg_bf;
  } else if (b < 16688) {
    b -= 15512; src = wf; dst = wf_bf;
  } else {  // zero logit: 8 blocks x 256 thr x 8 f32 = 16384
    b -= 16688;
    const size_t base = ((size_t)b * 256 + threadIdx.x) * 8;
    f32x8 z;
#pragma unroll
    for (int k = 0; k < 8; ++k) z[k] = 0.f;
    *(f32x8*)(logit + base) = z;
    return;
  }
  const size_t base = ((size_t)b * 256 + threadIdx.x) * 8;
  const f32x8 v = *(const f32x8*)(src + base);
  u16x8 o;
#pragma unroll
  for (int k = 0; k < 8; ++k) o[k] = f2bf(v[k]);
  *(u16x8*)(dst + base) = o;
}

// Stage one 128x64 half-tile with 512 threads (2 x gl_lds16 per thread),
// same pre-swizzled-source layout as the proven 465us kernel.
__device__ __forceinline__ void stage_half8(const unsigned short* __restrict__ g,
                                            int ld, int r0, int c0,
                                            unsigned short* lds, int tid) {
  const int w = tid >> 6, l = tid & 63;
  const int lrow = l >> 3;                 // row within 8-row segment
  const int lcol = ((l & 7) ^ lrow) * 8;   // swizzled source chunk
#pragma unroll
  for (int i = 0; i < 2; ++i) {
    const int seg = i * 8 + w;             // 16 segments x 8 rows = 128
    const int r = seg * 8 + lrow;
    gl_lds16((const void*)(g + (size_t)(r0 + r) * ld + (c0 + lcol)),
             (void*)(lds + seg * 512));    // HW adds lane*16B
  }
}

#define PH_BARRIER()                      \
  do {                                    \
    __builtin_amdgcn_s_barrier();         \
    __builtin_amdgcn_sched_barrier(0);    \
  } while (0)
#define PH_LGKM0()                                       \
  do {                                                   \
    asm volatile("s_waitcnt lgkmcnt(0)" ::: "memory");   \
    __builtin_amdgcn_sched_barrier(0);                   \
  } while (0)
#define PH_VM(n)                                          \
  do {                                                    \
    asm volatile("s_waitcnt vmcnt(" #n ")" ::: "memory"); \
    __builtin_amdgcn_sched_barrier(0);                    \
  } while (0)

// Flat LDS: sA = smem[0..32767], sB = smem[32768..65535] (u16 units).
#define sAp(b, h) (smem + ((b) * 2 + (h)) * 8192)
#define sBp(b, h) (smem + 32768 + ((b) * 2 + (h)) * 8192)

#define LDA_QS(dst, b, q)                                                    \
  _Pragma("unroll") for (int ii = 0; ii < 2; ++ii)                           \
      _Pragma("unroll") for (int ks = 0; ks < 2; ++ks) dst[ii][ks] =         \
      ld8(sAp(b, wm) + ((q) * 32 + ii * 16 + lane16) * 64 +                  \
          (((ks * 4 + quad) ^ sw) * 8));

#define LDB_ALL(b)                                                           \
  _Pragma("unroll") for (int jj = 0; jj < 4; ++jj)                           \
      _Pragma("unroll") for (int ks = 0; ks < 2; ++ks) fb[jj][ks] =          \
      ld8(sBp(b, wnh) + (wnl * 64 + jj * 16 + lane16) * 64 +                 \
          (((ks * 4 + quad) ^ sw) * 8));

#define MFMA_Q(ACC, q, FA)                                                   \
  __builtin_amdgcn_s_setprio(1);                                             \
  _Pragma("unroll") for (int ks = 0; ks < 2; ++ks)                           \
      _Pragma("unroll") for (int ii = 0; ii < 2; ++ii)                       \
          _Pragma("unroll") for (int jj = 0; jj < 4; ++jj) ACC[(q)*2 + ii]   \
      [jj] = __builtin_amdgcn_mfma_f32_16x16x32_bf16(                        \
          FA[ii][ks], fb[jj][ks], ACC[(q)*2 + ii][jj], 0, 0, 0);             \
  __builtin_amdgcn_s_setprio(0);

#define STAGE_A(kt, half)                                                    \
  {                                                                          \
    const int k0_ = (kt) * 64;                                               \
    const unsigned short* Ap_;                                               \
    int ac_;                                                                 \
    if constexpr (MODE == 0) {                                               \
      Ap_ = A0; ac_ = k0_;                                                   \
    } else if constexpr (MODE == 1) {                                        \
      if (k0_ < 896) { Ap_ = A0; ac_ = k0_; }                                \
      else { Ap_ = A1; ac_ = k0_ - 896; }                                    \
    } else {                                                                 \
      if (k0_ < 896) { Ap_ = A0; ac_ = k0_; }                                \
      else if (k0_ < 1792) { Ap_ = A1; ac_ = k0_ - 896; }                    \
      else { Ap_ = A2; ac_ = k0_ - 1792; }                                   \
    }                                                                        \
    stage_half8(Ap_, 896, row0 + (half) * 128, ac_, sAp((kt) & 1, half),     \
                tid);                                                        \
  }
#define STAGE_B(kt, half)                                                    \
  stage_half8(W, ldw, col0 + (half) * 128, (kt) * 64, sBp((kt) & 1, half),   \
              tid)

// One outer iteration (2 K-tiles, 8 phases). Reads for quad q+1 issue after
// MFMA of quad q (overlap LDS drain with MFMA drain). Buf-swap head reads
// (P0/P4) stay serial: cross-wave staging completion is only guaranteed by
// the preceding vmcnt + barrier.
#define GROUP8(ACC)                                                          \
  {                                                                          \
    const int c0t = 2 * t;                                                   \
    const int c1t = 2 * t + 1;                                               \
    const bool more = (t + 1 < NIT);                                         \
    /* P0 */                                                                 \
    LDB_ALL(0);                                                              \
    LDA_QS(faA, 0, 0);                                                       \
    STAGE_A(c1t, 0);                                                         \
    PH_BARRIER();                                                            \
    PH_LGKM0();                                                              \
    MFMA_Q(ACC, 0, faA);                                                     \
    LDA_QS(faB, 0, 1);                                                       \
    PH_BARRIER();                                                            \
    /* P1 */                                                                 \
    STAGE_A(c1t, 1);                                                         \
    PH_BARRIER();                                                            \
    PH_LGKM0();                                                              \
    MFMA_Q(ACC, 1, faB);                                                     \
    LDA_QS(faA, 0, 2);                                                       \
    PH_BARRIER();                                                            \
    /* P2 */                                                                 \
    if (more) STAGE_B(c0t + 2, 0);                                           \
    PH_BARRIER();                                                            \
    PH_LGKM0();                                                              \
    MFMA_Q(ACC, 2, faA);                                                     \
    LDA_QS(faB, 0, 3);                                                       \
    PH_BARRIER();                                                            \
    /* P3: vmcnt guarantees buf1 fully staged before P4's ds_reads */        \
    if (more) STAGE_B(c0t + 2, 1);                                           \
    PH_BARRIER();                                                            \
    PH_LGKM0();                                                              \
    MFMA_Q(ACC, 3, faB);                                                     \
    if (more) {                                                              \
      PH_VM(4);                                                              \
    } else {                                                                 \
      PH_VM(0);                                                              \
    }                                                                        \
    PH_BARRIER();                                                            \
    /* P4 */                                                                 \
    LDB_ALL(1);                                                              \
    LDA_QS(faA, 1, 0);                                                       \
    if (more) STAGE_A(c0t + 2, 0);                                           \
    PH_BARRIER();                                                            \
    PH_LGKM0();                                                              \
    MFMA_Q(ACC, 0, faA);                                                     \
    LDA_QS(faB, 1, 1);                                                       \
    PH_BARRIER();                                                            \
    /* P5 */                                                                 \
    if (more) STAGE_A(c0t + 2, 1);                                           \
    PH_BARRIER();                                                            \
    PH_LGKM0();                                                              \
    MFMA_Q(ACC, 1, faB);                                                     \
    LDA_QS(faA, 1, 2);                                                       \
    PH_BARRIER();                                                            \
    /* P6 */                                                                 \
    if (more) STAGE_B(c1t + 2, 0);                                           \
    PH_BARRIER();                                                            \
    PH_LGKM0();                                                              \
    MFMA_Q(ACC, 2, faA);                                                     \
    LDA_QS(faB, 1, 3);                                                       \
    PH_BARRIER();                                                            \
    /* P7 */                                                                 \
    if (more) STAGE_B(c1t + 2, 1);                                           \
    PH_BARRIER();                                                            \
    PH_LGKM0();                                                              \
    MFMA_Q(ACC, 3, faB);                                                     \
    if (more) PH_VM(4);                                                      \
    PH_BARRIER();                                                            \
  }

// MODE 0: C = u @ Wa^T; epi: logit[row] += sum_col (C+b)*h   (LDS-reduced)
// MODE 1: C = h@Wl^T + a*(u@Wr^T); epi: ug = sigmoid(C+b)*a*u; hu = h*ug
// MODE 2: C = [h|ug|hu] @ Wf^T; epi: out = gelu_erf(C+b)
template <int MODE, int NKT>
__global__ __launch_bounds__(512, 2) void gemm8(
    const unsigned short* __restrict__ A0, const unsigned short* __restrict__ A1,
    const unsigned short* __restrict__ A2, const unsigned short* __restrict__ W,
    int ldw, const float* __restrict__ bias,
    const unsigned short* __restrict__ hx, float* __restrict__ logit,
    unsigned short* __restrict__ ug_out, unsigned short* __restrict__ hu_out,
    float* __restrict__ fout) {
  __shared__ unsigned short smem[65536];  // 128 KiB: sA 64K | sB 64K
  constexpr int NIT = NKT / 2;
  const int tid = threadIdx.x;
  const int w = tid >> 6, l = tid & 63;
  const int quad = l >> 4, lane16 = l & 15;
  const int sw = lane16 & 7;
  const int wm = w >> 2;            // 0..1  (row half)
  const int wn = w & 3;             // 0..3  (col quarter)
  const int wnh = wn >> 1, wnl = wn & 1;
  const int bid = blockIdx.x;
  const int row0 = (bid & 63) * 256;
  const int col0 = (bid >> 6) * 256;

  f32x4 acc[8][4];
#pragma unroll
  for (int i = 0; i < 8; ++i)
#pragma unroll
    for (int j = 0; j < 4; ++j) acc[i][j] = f32x4{0.f, 0.f, 0.f, 0.f};
  f32x4 accU[8][4];
  if constexpr (MODE == 1) {
#pragma unroll
    for (int i = 0; i < 8; ++i)
#pragma unroll
      for (int j = 0; j < 4; ++j) accU[i][j] = f32x4{0.f, 0.f, 0.f, 0.f};
  }

  bf16x8 faA[2][2], faB[2][2], fb[4][2];

  // Prologue: stage B(0).h0,h1 A(0).h0,h1 B(1).h0,h1 (12 loads); leave B(1)
  // in flight (vmcnt(4) retires everything buf0 needs).
  STAGE_B(0, 0);
  STAGE_B(0, 1);
  STAGE_A(0, 0);
  STAGE_A(0, 1);
  STAGE_B(1, 0);
  STAGE_B(1, 1);
  PH_VM(4);
  PH_BARRIER();

  if constexpr (MODE == 1) {
    // K-tiles 0..13 = h-part (acc), 14..27 = u-part (accU); NIT=14, split t=7.
    for (int t = 0; t < 7; ++t) GROUP8(acc);
    for (int t = 7; t < NIT; ++t) GROUP8(accU);
  } else {
    for (int t = 0; t < NIT; ++t) GROUP8(acc);
  }

  // Epilogue. cols >= 896 are padding (garbage weights) -> guarded out.
  float bj[4];
  bool bv[4];
#pragma unroll
  for (int j = 0; j < 4; ++j) {
    const int col = col0 + wn * 64 + j * 16 + lane16;
    bv[j] = (col < 896);
    bj[j] = bv[j] ? bias[col] : 0.f;
  }

  if constexpr (MODE == 0) {
    // LDS cross-wave reduction: 4 wn-waves hold partials for the SAME rows.
    float* red = (float*)smem;  // 256*4 floats = 4 KiB (smem is dead)
#pragma unroll
    for (int i = 0; i < 8; ++i) {
#pragma unroll
      for (int r = 0; r < 4; ++r) {
        const int rl = wm * 128 + i * 16 + quad * 4 + r;
        const int row = row0 + rl;
        float s = 0.f;
#pragma unroll
        for (int j = 0; j < 4; ++j) {
          if (bv[j]) {
            const int col = col0 + wn * 64 + j * 16 + lane16;
            s += (acc[i][j][r] + bj[j]) * b2f(hx[(size_t)row * D + col]);
          }
        }
        s += __shfl_xor(s, 1, 64);
        s += __shfl_xor(s, 2, 64);
        s += __shfl_xor(s, 4, 64);
        s += __shfl_xor(s, 8, 64);
        if (lane16 == 0) red[rl * 4 + wn] = s;
      }
    }
    __syncthreads();
    if (tid < 256) {
      const float v =
          red[tid * 4 + 0] + red[tid * 4 + 1] + red[tid * 4 + 2] + red[tid * 4 + 3];
      atomicAdd(logit + row0 + tid, v);
    }
  } else {
    // LDS-transposed epilogue: dump x to row-major [64][276] f32 (stride 276
    // -> conflict-free: quad flips +16 banks, lane16 walks +1), then read
    // row-contiguous and do vectorized global IO. 4 chunks x 64 rows.
    float* xbuf = (float*)smem;  // 64*276*4 = 70656 B <= 128 KiB
    const int tr = tid >> 3;     // 0..63: row within chunk
    const int tc = tid & 7;      // col-lane
    for (int c = 0; c < 4; ++c) {
      if (wm == (c >> 1)) {      // wave-uniform: this half owns chunk rows
        const int ibase = (c & 1) * 4;
#pragma unroll
        for (int i2 = 0; i2 < 4; ++i2) {
          const int i = ibase + i2;
#pragma unroll
          for (int r = 0; r < 4; ++r) {
            const int rl = i2 * 16 + quad * 4 + r;
            float al;
            if constexpr (MODE == 1)
              al = sigmoidf_(logit[row0 + c * 64 + rl] * INV_SQRT_D);
#pragma unroll
            for (int j = 0; j < 4; ++j) {
              float x = acc[i][j][r] + bj[j];
              if constexpr (MODE == 1) x += al * accU[i][j][r];
              xbuf[rl * 276 + wn * 64 + j * 16 + lane16] = x;
            }
          }
        }
      }
      __syncthreads();
      const int grow = row0 + c * 64 + tr;
      if constexpr (MODE == 1) {
        const float alr = sigmoidf_(logit[grow] * INV_SQRT_D);
#pragma unroll
        for (int s = 0; s < 4; ++s) {
          const int lc = tc * 8 + s * 64;
          const int gcol = col0 + lc;
          if (gcol < 896) {
            const size_t gidx = (size_t)grow * D + gcol;
            const f32x4 xa = *(const f32x4*)&xbuf[tr * 276 + lc];
            const f32x4 xb = *(const f32x4*)&xbuf[tr * 276 + lc + 4];
            const u16x8 uv = *(const u16x8*)(A1 + gidx);
            const u16x8 hv = *(const u16x8*)(A0 + gidx);
            u16x8 ugv, huv;
#pragma unroll
            for (int k = 0; k < 8; ++k) {
              const float x = (k < 4) ? xa[k] : xb[k - 4];
              const float ug = sigmoidf_(x) * alr * b2f(uv[k]);
              ugv[k] = f2bf(ug);
              huv[k] = f2bf(b2f(hv[k]) * ug);
            }
            *(u16x8*)(ug_out + gidx) = ugv;
            *(u16x8*)(hu_out + gidx) = huv;
          }
        }
      } else {
#pragma unroll
        for (int s = 0; s < 8; ++s) {
          const int lc = tc * 4 + s * 32;
          const int gcol = col0 + lc;
          if (gcol < 896) {
            const f32x4 xa = *(const f32x4*)&xbuf[tr * 276 + lc];
            f32x4 o;
#pragma unroll
            for (int k = 0; k < 4; ++k)
              o[k] = 0.5f * xa[k] * (1.f + erff(xa[k] * 0.70710678118654752f));
            *(f32x4*)(fout + (size_t)grow * D + gcol) = o;
          }
        }
      }
      __syncthreads();
    }
  }
}

// ================== PLAN B (fallback, ws too small): R4 path ================

__device__ __forceinline__ void stage_f32_f(const float* __restrict__ g, int ld,
                                            int row0, int col0,
                                            unsigned short* lds, int tid) {
#pragma unroll
  for (int i = 0; i < 4; ++i) {
    const int idx = i * 256 + tid;
    const int r = idx >> 3, c8 = (idx & 7) * 8;
    const f32x8 v = *(const f32x8*)(g + (size_t)(row0 + r) * ld + (col0 + c8));
    u16x8 o;
#pragma unroll
    for (int k = 0; k < 8; ++k) o[k] = f2bf(v[k]);
    *(u16x8*)(lds + r * 64 + c8) = o;
  }
}
__device__ __forceinline__ void stage_att_f(const float* __restrict__ u_t,
                                            const float* __restrict__ logit,
                                            int row0, int col0,
                                            unsigned short* lds, int tid) {
#pragma unroll
  for (int i = 0; i < 4; ++i) {
    const int idx = i * 256 + tid;
    const int r = idx >> 3, c8 = (idx & 7) * 8;
    const float a = sigmoidf_(logit[row0 + r] * INV_SQRT_D);
    const f32x8 v = *(const f32x8*)(u_t + (size_t)(row0 + r) * D + (col0 + c8));
    u16x8 o;
#pragma unroll
    for (int k = 0; k < 8; ++k) o[k] = f2bf(v[k] * a);
    *(u16x8*)(lds + r * 64 + c8) = o;
  }
}
__device__ __forceinline__ void stage_bf16_f(const unsigned short* __restrict__ g,
                                             int row0, int col0,
                                             unsigned short* lds, int tid) {
#pragma unroll
  for (int i = 0; i < 4; ++i) {
    const int idx = i * 256 + tid;
    const int r = idx >> 3, c8 = (idx & 7) * 8;
    *(u16x8*)(lds + r * 64 + c8) =
        *(const u16x8*)(g + (size_t)(row0 + r) * D + (col0 + c8));
  }
}
__device__ __forceinline__ void stage_mul_f(const float* __restrict__ h,
                                            const unsigned short* __restrict__ ug,
                                            int row0, int col0,
                                            unsigned short* lds, int tid) {
#pragma unroll
  for (int i = 0; i < 4; ++i) {
    const int idx = i * 256 + tid;
    const int r = idx >> 3, c8 = (idx & 7) * 8;
    const size_t off = (size_t)(row0 + r) * D + (col0 + c8);
    const f32x8 vh = *(const f32x8*)(h + off);
    const u16x8 vu = *(const u16x8*)(ug + off);
    u16x8 o;
#pragma unroll
    for (int k = 0; k < 8; ++k) o[k] = f2bf(vh[k] * b2f(vu[k]));
    *(u16x8*)(lds + r * 64 + c8) = o;
  }
}

template <int MODE, int KITERS>
__global__ __launch_bounds__(256) void gemm_f(
    const float* __restrict__ A0, const float* __restrict__ A1,
    const unsigned short* __restrict__ Ab, const float* __restrict__ W, int ldw,
    const float* __restrict__ bias, float* __restrict__ logit,
    unsigned short* __restrict__ ug_out, float* __restrict__ fout) {
  __shared__ unsigned short sA[128 * 64];
  __shared__ unsigned short sB[128 * 64];
  const int tid = threadIdx.x;
  const int w = tid >> 6, l = tid & 63;
  const int quad = l >> 4, lane16 = l & 15;
  const int wrow = (w >> 1) * 64, wcol = (w & 1) * 64;
  const int row0 = (blockIdx.x & 127) * 128;
  const int col0 = (blockIdx.x >> 7) * 128;

  f32x4 acc[4][4];
#pragma unroll
  for (int i = 0; i < 4; ++i)
#pragma unroll
    for (int j = 0; j < 4; ++j) acc[i][j] = f32x4{0.f, 0.f, 0.f, 0.f};

  for (int kt = 0; kt < KITERS; ++kt) {
    const int k0 = kt * 64;
    if constexpr (MODE == 0) {
      stage_f32_f(A0, D, row0, k0, sA, tid);
    } else if constexpr (MODE == 1) {
      if (k0 < 896) stage_f32_f(A0, D, row0, k0, sA, tid);
      else stage_att_f(A1, logit, row0, k0 - 896, sA, tid);
    } else {
      if (k0 < 896) stage_f32_f(A0, D, row0, k0, sA, tid);
      else if (k0 < 1792) stage_bf16_f(Ab, row0, k0 - 896, sA, tid);
      else stage_mul_f(A0, Ab, row0, k0 - 1792, sA, tid);
    }
    stage_f32_f(W, ldw, col0, k0, sB, tid);
    __syncthreads();
#pragma unroll
    for (int ks = 0; ks < 2; ++ks) {
      bf16x8 fa[4], fb[4];
#pragma unroll
      for (int t = 0; t < 4; ++t) {
        fa[t] = ld8(sA + (wrow + t * 16 + lane16) * 64 + ks * 32 + quad * 8);
        fb[t] = ld8(sB + (wcol + t * 16 + lane16) * 64 + ks * 32 + quad * 8);
      }
#pragma unroll
      for (int i = 0; i < 4; ++i)
#pragma unroll
        for (int j = 0; j < 4; ++j)
          acc[i][j] = __builtin_amdgcn_mfma_f32_16x16x32_bf16(fa[i], fb[j], acc[i][j], 0, 0, 0);
    }
    __syncthreads();
  }

  float bj[4];
#pragma unroll
  for (int j = 0; j < 4; ++j) bj[j] = bias[col0 + wcol + j * 16 + lane16];

  if constexpr (MODE == 0) {
#pragma unroll
    for (int i = 0; i < 4; ++i) {
#pragma unroll
      for (int r = 0; r < 4; ++r) {
        const int row = row0 + wrow + i * 16 + quad * 4 + r;
        float s = 0.f;
#pragma unroll
        for (int j = 0; j < 4; ++j) {
          const int col = col0 + wcol + j * 16 + lane16;
          s += (acc[i][j][r] + bj[j]) * A1[(size_t)row * D + col];
        }
        s += __shfl_xor(s, 1, 64);
        s += __shfl_xor(s, 2, 64);
        s += __shfl_xor(s, 4, 64);
        s += __shfl_xor(s, 8, 64);
        if (lane16 == 0) atomicAdd(logit + row, s);
      }
    }
  } else {
#pragma unroll
    for (int i = 0; i < 4; ++i) {
#pragma unroll
      for (int r = 0; r < 4; ++r) {
        const int row = row0 + wrow + i * 16 + quad * 4 + r;
        float alpha;
        if constexpr (MODE == 1) alpha = sigmoidf_(logit[row] * INV_SQRT_D);
#pragma unroll
        for (int j = 0; j < 4; ++j) {
          const int col = col0 + wcol + j * 16 + lane16;
          const size_t idx = (size_t)row * D + col;
          const float x = acc[i][j][r] + bj[j];
          if constexpr (MODE == 1) {
            ug_out[idx] = f2bf(sigmoidf_(x) * alpha * A1[idx]);
          } else {
            fout[idx] = 0.5f * x * (1.f + erff(x * 0.70710678118654752f));
          }
        }
      }
    }
  }
}

// ============================================================================

extern "C" void kernel_launch(void* const* d_in, const int* in_sizes, int n_in,
                              void* d_out, int out_size, void* d_ws, size_t ws_size,
                              hipStream_t stream) {
  const float* h_t = (const float*)d_in[0];
  const float* u_t = (const float*)d_in[1];
  const float* W_a_w = (const float*)d_in[4];
  const float* W_a_b = (const float*)d_in[5];
  const float* W_g_w = (const float*)d_in[6];
  const float* W_g_b = (const float*)d_in[7];
  const float* W_f_w = (const float*)d_in[8];
  const float* W_f_b = (const float*)d_in[9];
  float* out = (float*)d_out;

  // Plan A scratch layout (bytes). Weights UNPADDED: col-panel-3 stage reads
  // of rows 896..1023 spill into the next allocation (garbage -> masked cols):
  //   wa_bf  bf16[896*896]   @ 0          (spill -> wg_bf, ok)
  //   wg_bf  bf16[896*1792]  @ 1605632    (spill -> wf_bf, ok)
  //   wf_bf  bf16[896*2688]  @ 4816896    (spill -> h_bf, ok)
  //   h_bf   bf16[N*D]       @ 9633792
  //   u_bf   bf16[N*D]       @ 38993920   (stays RAW u; alpha fused in MODE1)
  //   ug_bf  bf16[N*D]       @ 68354048
  //   hu_bf  bf16[N*D]       @ 97714176   -> end 127074304
  //   logit  f32[16384]      -> d_out front (dead before MODE2 overwrites)
  const size_t NEED = 127074304;

  if (ws_size >= NEED) {
    char* ws = (char*)d_ws;
    unsigned short* wa_bf = (unsigned short*)ws;
    unsigned short* wg_bf = (unsigned short*)(ws + 1605632);
    unsigned short* wf_bf = (unsigned short*)(ws + 4816896);
    unsigned short* h_bf = (unsigned short*)(ws + 9633792);
    unsigned short* u_bf = (unsigned short*)(ws + 38993920);
    unsigned short* ug_bf = (unsigned short*)(ws + 68354048);
    unsigned short* hu_bf = (unsigned short*)(ws + 97714176);
    float* logit = (float*)d_out;

    prep_k<<<dim3(16696), dim3(256), 0, stream>>>(h_t, u_t, W_a_w, W_g_w, W_f_w,
                                                  h_bf, u_bf, wa_bf, wg_bf,
                                                  wf_bf, logit);
    gemm8<0, 14><<<dim3(256), dim3(512), 0, stream>>>(
        u_bf, nullptr, nullptr, wa_bf, 896, W_a_b, h_bf, logit, nullptr,
        nullptr, nullptr);
    gemm8<1, 28><<<dim3(256), dim3(512), 0, stream>>>(
        h_bf, u_bf, nullptr, wg_bf, 1792, W_g_b, nullptr, logit, ug_bf,
        hu_bf, nullptr);
    gemm8<2, 42><<<dim3(256), dim3(512), 0, stream>>>(
        h_bf, ug_bf, hu_bf, wf_bf, 2688, W_f_b, nullptr, nullptr, nullptr,
        nullptr, out);
  } else {
    // Fallback (proven R4 path): logit in d_out front, u_gate in u_all buffer.
    unsigned short* u_gate = (unsigned short*)d_in[3];
    float* logit = (float*)d_out;
    const dim3 blk(256);
    const dim3 grid(128 * 7);
    hipMemsetAsync(d_out, 0, NTOK * sizeof(float), stream);
    gemm_f<0, 14><<<grid, blk, 0, stream>>>(u_t, h_t, nullptr, W_a_w, 896, W_a_b,
                                            logit, nullptr, nullptr);
    gemm_f<1, 28><<<grid, blk, 0, stream>>>(h_t, u_t, nullptr, W_g_w, 1792, W_g_b,
                                            logit, u_gate, nullptr);
    gemm_f<2, 42><<<grid, blk, 0, stream>>>(h_t, nullptr, u_gate, W_f_w, 2688,
                                            W_f_b, nullptr, nullptr, out);
  }
}

// Round 6
// 441.393 us; speedup vs baseline: 1.2100x; 1.2100x over previous
//
#include <hip/hip_runtime.h>
#include <math.h>

#define D 896
#define NTOK 16384
#define INV_SQRT_D 0.03340766f  // 1/sqrt(896)

typedef __bf16 bf16x8 __attribute__((ext_vector_type(8)));
typedef float f32x4 __attribute__((ext_vector_type(4)));
typedef float f32x8 __attribute__((ext_vector_type(8)));
typedef unsigned short u16x8 __attribute__((ext_vector_type(8)));

__device__ __forceinline__ float sigmoidf_(float x) {
  return 1.f / (1.f + __expf(-x));
}
__device__ __forceinline__ float b2f(unsigned short u) {
  return __uint_as_float(((unsigned int)u) << 16);
}
__device__ __forceinline__ unsigned short f2bf(float f) {
  const unsigned int u = __float_as_uint(f);
  return (unsigned short)((u + 0x7fffu + ((u >> 16) & 1u)) >> 16);
}
__device__ __forceinline__ bf16x8 ld8(const unsigned short* p) {
  return __builtin_bit_cast(bf16x8, *(const u16x8*)p);
}
__device__ __forceinline__ void gl_lds16(const void* g, void* l) {
  __builtin_amdgcn_global_load_lds(
      (const __attribute__((address_space(1))) void*)g,
      (__attribute__((address_space(3))) void*)l, 16, 0, 0);
}

// ===================== PLAN A: 256x256 8-phase bf16 GEMM =====================
// R6 = R5 with ONE fix: the epilogue chunk loop is now #pragma unroll'd.
// R5's runtime `c` made acc[ibase+i2] a runtime-indexed ext_vector array ->
// compiler demoted BOTH accumulators to scratch (measured: WRITE_SIZE 519MB
// = 9x ideal, MfmaUtil 26->15%). Rule #20: static indexing via full unroll.

// Fused f32->bf16 conversions (h, u, Wa, Wg, Wf) + logit zero, one launch.
__global__ __launch_bounds__(256) void prep_k(
    const float* __restrict__ h, const float* __restrict__ u,
    const float* __restrict__ wa, const float* __restrict__ wg,
    const float* __restrict__ wf, unsigned short* __restrict__ h_bf,
    unsigned short* __restrict__ u_bf, unsigned short* __restrict__ wa_bf,
    unsigned short* __restrict__ wg_bf, unsigned short* __restrict__ wf_bf,
    float* __restrict__ logit) {
  int b = blockIdx.x;
  const float* src;
  unsigned short* dst;
  if (b < 7168) {
    src = h; dst = h_bf;
  } else if (b < 14336) {
    b -= 7168; src = u; dst = u_bf;
  } else if (b < 14728) {
    b -= 14336; src = wa; dst = wa_bf;
  } else if (b < 15512) {
    b -= 14728; src = wg; dst = wg_bf;
  } else if (b < 16688) {
    b -= 15512; src = wf; dst = wf_bf;
  } else {  // zero logit: 8 blocks x 256 thr x 8 f32 = 16384
    b -= 16688;
    const size_t base = ((size_t)b * 256 + threadIdx.x) * 8;
    f32x8 z;
#pragma unroll
    for (int k = 0; k < 8; ++k) z[k] = 0.f;
    *(f32x8*)(logit + base) = z;
    return;
  }
  const size_t base = ((size_t)b * 256 + threadIdx.x) * 8;
  const f32x8 v = *(const f32x8*)(src + base);
  u16x8 o;
#pragma unroll
  for (int k = 0; k < 8; ++k) o[k] = f2bf(v[k]);
  *(u16x8*)(dst + base) = o;
}

// Stage one 128x64 half-tile with 512 threads (2 x gl_lds16 per thread),
// same pre-swizzled-source layout as the proven 465us kernel.
__device__ __forceinline__ void stage_half8(const unsigned short* __restrict__ g,
                                            int ld, int r0, int c0,
                                            unsigned short* lds, int tid) {
  const int w = tid >> 6, l = tid & 63;
  const int lrow = l >> 3;                 // row within 8-row segment
  const int lcol = ((l & 7) ^ lrow) * 8;   // swizzled source chunk
#pragma unroll
  for (int i = 0; i < 2; ++i) {
    const int seg = i * 8 + w;             // 16 segments x 8 rows = 128
    const int r = seg * 8 + lrow;
    gl_lds16((const void*)(g + (size_t)(r0 + r) * ld + (c0 + lcol)),
             (void*)(lds + seg * 512));    // HW adds lane*16B
  }
}

#define PH_BARRIER()                      \
  do {                                    \
    __builtin_amdgcn_s_barrier();         \
    __builtin_amdgcn_sched_barrier(0);    \
  } while (0)
#define PH_LGKM0()                                       \
  do {                                                   \
    asm volatile("s_waitcnt lgkmcnt(0)" ::: "memory");   \
    __builtin_amdgcn_sched_barrier(0);                   \
  } while (0)
#define PH_VM(n)                                          \
  do {                                                    \
    asm volatile("s_waitcnt vmcnt(" #n ")" ::: "memory"); \
    __builtin_amdgcn_sched_barrier(0);                    \
  } while (0)

// Flat LDS: sA = smem[0..32767], sB = smem[32768..65535] (u16 units).
#define sAp(b, h) (smem + ((b) * 2 + (h)) * 8192)
#define sBp(b, h) (smem + 32768 + ((b) * 2 + (h)) * 8192)

#define LDA_QS(dst, b, q)                                                    \
  _Pragma("unroll") for (int ii = 0; ii < 2; ++ii)                           \
      _Pragma("unroll") for (int ks = 0; ks < 2; ++ks) dst[ii][ks] =         \
      ld8(sAp(b, wm) + ((q) * 32 + ii * 16 + lane16) * 64 +                  \
          (((ks * 4 + quad) ^ sw) * 8));

#define LDB_ALL(b)                                                           \
  _Pragma("unroll") for (int jj = 0; jj < 4; ++jj)                           \
      _Pragma("unroll") for (int ks = 0; ks < 2; ++ks) fb[jj][ks] =          \
      ld8(sBp(b, wnh) + (wnl * 64 + jj * 16 + lane16) * 64 +                 \
          (((ks * 4 + quad) ^ sw) * 8));

#define MFMA_Q(ACC, q, FA)                                                   \
  __builtin_amdgcn_s_setprio(1);                                             \
  _Pragma("unroll") for (int ks = 0; ks < 2; ++ks)                           \
      _Pragma("unroll") for (int ii = 0; ii < 2; ++ii)                       \
          _Pragma("unroll") for (int jj = 0; jj < 4; ++jj) ACC[(q)*2 + ii]   \
      [jj] = __builtin_amdgcn_mfma_f32_16x16x32_bf16(                        \
          FA[ii][ks], fb[jj][ks], ACC[(q)*2 + ii][jj], 0, 0, 0);             \
  __builtin_amdgcn_s_setprio(0);

#define STAGE_A(kt, half)                                                    \
  {                                                                          \
    const int k0_ = (kt) * 64;                                               \
    const unsigned short* Ap_;                                               \
    int ac_;                                                                 \
    if constexpr (MODE == 0) {                                               \
      Ap_ = A0; ac_ = k0_;                                                   \
    } else if constexpr (MODE == 1) {                                        \
      if (k0_ < 896) { Ap_ = A0; ac_ = k0_; }                                \
      else { Ap_ = A1; ac_ = k0_ - 896; }                                    \
    } else {                                                                 \
      if (k0_ < 896) { Ap_ = A0; ac_ = k0_; }                                \
      else if (k0_ < 1792) { Ap_ = A1; ac_ = k0_ - 896; }                    \
      else { Ap_ = A2; ac_ = k0_ - 1792; }                                   \
    }                                                                        \
    stage_half8(Ap_, 896, row0 + (half) * 128, ac_, sAp((kt) & 1, half),     \
                tid);                                                        \
  }
#define STAGE_B(kt, half)                                                    \
  stage_half8(W, ldw, col0 + (half) * 128, (kt) * 64, sBp((kt) & 1, half),   \
              tid)

// One outer iteration (2 K-tiles, 8 phases). Reads for quad q+1 issue after
// MFMA of quad q (overlap LDS drain with MFMA drain). Buf-swap head reads
// (P0/P4) stay serial: cross-wave staging completion is only guaranteed by
// the preceding vmcnt + barrier.
#define GROUP8(ACC)                                                          \
  {                                                                          \
    const int c0t = 2 * t;                                                   \
    const int c1t = 2 * t + 1;                                               \
    const bool more = (t + 1 < NIT);                                         \
    /* P0 */                                                                 \
    LDB_ALL(0);                                                              \
    LDA_QS(faA, 0, 0);                                                       \
    STAGE_A(c1t, 0);                                                         \
    PH_BARRIER();                                                            \
    PH_LGKM0();                                                              \
    MFMA_Q(ACC, 0, faA);                                                     \
    LDA_QS(faB, 0, 1);                                                       \
    PH_BARRIER();                                                            \
    /* P1 */                                                                 \
    STAGE_A(c1t, 1);                                                         \
    PH_BARRIER();                                                            \
    PH_LGKM0();                                                              \
    MFMA_Q(ACC, 1, faB);                                                     \
    LDA_QS(faA, 0, 2);                                                       \
    PH_BARRIER();                                                            \
    /* P2 */                                                                 \
    if (more) STAGE_B(c0t + 2, 0);                                           \
    PH_BARRIER();                                                            \
    PH_LGKM0();                                                              \
    MFMA_Q(ACC, 2, faA);                                                     \
    LDA_QS(faB, 0, 3);                                                       \
    PH_BARRIER();                                                            \
    /* P3: vmcnt guarantees buf1 fully staged before P4's ds_reads */        \
    if (more) STAGE_B(c0t + 2, 1);                                           \
    PH_BARRIER();                                                            \
    PH_LGKM0();                                                              \
    MFMA_Q(ACC, 3, faB);                                                     \
    if (more) {                                                              \
      PH_VM(4);                                                              \
    } else {                                                                 \
      PH_VM(0);                                                              \
    }                                                                        \
    PH_BARRIER();                                                            \
    /* P4 */                                                                 \
    LDB_ALL(1);                                                              \
    LDA_QS(faA, 1, 0);                                                       \
    if (more) STAGE_A(c0t + 2, 0);                                           \
    PH_BARRIER();                                                            \
    PH_LGKM0();                                                              \
    MFMA_Q(ACC, 0, faA);                                                     \
    LDA_QS(faB, 1, 1);                                                       \
    PH_BARRIER();                                                            \
    /* P5 */                                                                 \
    if (more) STAGE_A(c0t + 2, 1);                                           \
    PH_BARRIER();                                                            \
    PH_LGKM0();                                                              \
    MFMA_Q(ACC, 1, faB);                                                     \
    LDA_QS(faA, 1, 2);                                                       \
    PH_BARRIER();                                                            \
    /* P6 */                                                                 \
    if (more) STAGE_B(c1t + 2, 0);                                           \
    PH_BARRIER();                                                            \
    PH_LGKM0();                                                              \
    MFMA_Q(ACC, 2, faA);                                                     \
    LDA_QS(faB, 1, 3);                                                       \
    PH_BARRIER();                                                            \
    /* P7 */                                                                 \
    if (more) STAGE_B(c1t + 2, 1);                                           \
    PH_BARRIER();                                                            \
    PH_LGKM0();                                                              \
    MFMA_Q(ACC, 3, faB);                                                     \
    if (more) PH_VM(4);                                                      \
    PH_BARRIER();                                                            \
  }

// MODE 0: C = u @ Wa^T; epi: logit[row] += sum_col (C+b)*h   (LDS-reduced)
// MODE 1: C = h@Wl^T + a*(u@Wr^T); epi: ug = sigmoid(C+b)*a*u; hu = h*ug
// MODE 2: C = [h|ug|hu] @ Wf^T; epi: out = gelu_erf(C+b)
template <int MODE, int NKT>
__global__ __launch_bounds__(512, 2) void gemm8(
    const unsigned short* __restrict__ A0, const unsigned short* __restrict__ A1,
    const unsigned short* __restrict__ A2, const unsigned short* __restrict__ W,
    int ldw, const float* __restrict__ bias,
    const unsigned short* __restrict__ hx, float* __restrict__ logit,
    unsigned short* __restrict__ ug_out, unsigned short* __restrict__ hu_out,
    float* __restrict__ fout) {
  __shared__ unsigned short smem[65536];  // 128 KiB: sA 64K | sB 64K
  constexpr int NIT = NKT / 2;
  const int tid = threadIdx.x;
  const int w = tid >> 6, l = tid & 63;
  const int quad = l >> 4, lane16 = l & 15;
  const int sw = lane16 & 7;
  const int wm = w >> 2;            // 0..1  (row half)
  const int wn = w & 3;             // 0..3  (col quarter)
  const int wnh = wn >> 1, wnl = wn & 1;
  const int bid = blockIdx.x;
  const int row0 = (bid & 63) * 256;
  const int col0 = (bid >> 6) * 256;

  f32x4 acc[8][4];
#pragma unroll
  for (int i = 0; i < 8; ++i)
#pragma unroll
    for (int j = 0; j < 4; ++j) acc[i][j] = f32x4{0.f, 0.f, 0.f, 0.f};
  f32x4 accU[8][4];
  if constexpr (MODE == 1) {
#pragma unroll
    for (int i = 0; i < 8; ++i)
#pragma unroll
      for (int j = 0; j < 4; ++j) accU[i][j] = f32x4{0.f, 0.f, 0.f, 0.f};
  }

  bf16x8 faA[2][2], faB[2][2], fb[4][2];

  // Prologue: stage B(0).h0,h1 A(0).h0,h1 B(1).h0,h1 (12 loads); leave B(1)
  // in flight (vmcnt(4) retires everything buf0 needs).
  STAGE_B(0, 0);
  STAGE_B(0, 1);
  STAGE_A(0, 0);
  STAGE_A(0, 1);
  STAGE_B(1, 0);
  STAGE_B(1, 1);
  PH_VM(4);
  PH_BARRIER();

  if constexpr (MODE == 1) {
    // K-tiles 0..13 = h-part (acc), 14..27 = u-part (accU); NIT=14, split t=7.
    for (int t = 0; t < 7; ++t) GROUP8(acc);
    for (int t = 7; t < NIT; ++t) GROUP8(accU);
  } else {
    for (int t = 0; t < NIT; ++t) GROUP8(acc);
  }

  // Epilogue. cols >= 896 are padding (garbage weights) -> guarded out.
  float bj[4];
  bool bv[4];
#pragma unroll
  for (int j = 0; j < 4; ++j) {
    const int col = col0 + wn * 64 + j * 16 + lane16;
    bv[j] = (col < 896);
    bj[j] = bv[j] ? bias[col] : 0.f;
  }

  if constexpr (MODE == 0) {
    // LDS cross-wave reduction: 4 wn-waves hold partials for the SAME rows.
    float* red = (float*)smem;  // 256*4 floats = 4 KiB (smem is dead)
#pragma unroll
    for (int i = 0; i < 8; ++i) {
#pragma unroll
      for (int r = 0; r < 4; ++r) {
        const int rl = wm * 128 + i * 16 + quad * 4 + r;
        const int row = row0 + rl;
        float s = 0.f;
#pragma unroll
        for (int j = 0; j < 4; ++j) {
          if (bv[j]) {
            const int col = col0 + wn * 64 + j * 16 + lane16;
            s += (acc[i][j][r] + bj[j]) * b2f(hx[(size_t)row * D + col]);
          }
        }
        s += __shfl_xor(s, 1, 64);
        s += __shfl_xor(s, 2, 64);
        s += __shfl_xor(s, 4, 64);
        s += __shfl_xor(s, 8, 64);
        if (lane16 == 0) red[rl * 4 + wn] = s;
      }
    }
    __syncthreads();
    if (tid < 256) {
      const float v =
          red[tid * 4 + 0] + red[tid * 4 + 1] + red[tid * 4 + 2] + red[tid * 4 + 3];
      atomicAdd(logit + row0 + tid, v);
    }
  } else {
    // LDS-transposed epilogue: dump x to row-major [64][276] f32 (stride 276
    // -> conflict-free dump), then read row-contiguous and do vectorized
    // global IO. 4 chunks x 64 rows. FULLY UNROLLED (rule #20: runtime chunk
    // index demotes acc to scratch — R5's 519MB WRITE_SIZE bug).
    float* xbuf = (float*)smem;  // 64*276*4 = 70656 B <= 128 KiB
    const int tr = tid >> 3;     // 0..63: row within chunk
    const int tc = tid & 7;      // col-lane
#pragma unroll
    for (int c = 0; c < 4; ++c) {
      if (wm == (c >> 1)) {      // wave-uniform: this half owns chunk rows
        const int ibase = (c & 1) * 4;
#pragma unroll
        for (int i2 = 0; i2 < 4; ++i2) {
          const int i = ibase + i2;
#pragma unroll
          for (int r = 0; r < 4; ++r) {
            const int rl = i2 * 16 + quad * 4 + r;
            float al;
            if constexpr (MODE == 1)
              al = sigmoidf_(logit[row0 + c * 64 + rl] * INV_SQRT_D);
#pragma unroll
            for (int j = 0; j < 4; ++j) {
              float x = acc[i][j][r] + bj[j];
              if constexpr (MODE == 1) x += al * accU[i][j][r];
              xbuf[rl * 276 + wn * 64 + j * 16 + lane16] = x;
            }
          }
        }
      }
      __syncthreads();
      const int grow = row0 + c * 64 + tr;
      if constexpr (MODE == 1) {
        const float alr = sigmoidf_(logit[grow] * INV_SQRT_D);
#pragma unroll
        for (int s = 0; s < 4; ++s) {
          const int lc = tc * 8 + s * 64;
          const int gcol = col0 + lc;
          if (gcol < 896) {
            const size_t gidx = (size_t)grow * D + gcol;
            const f32x4 xa = *(const f32x4*)&xbuf[tr * 276 + lc];
            const f32x4 xb = *(const f32x4*)&xbuf[tr * 276 + lc + 4];
            const u16x8 uv = *(const u16x8*)(A1 + gidx);
            const u16x8 hv = *(const u16x8*)(A0 + gidx);
            u16x8 ugv, huv;
#pragma unroll
            for (int k = 0; k < 8; ++k) {
              const float x = (k < 4) ? xa[k] : xb[k - 4];
              const float ug = sigmoidf_(x) * alr * b2f(uv[k]);
              ugv[k] = f2bf(ug);
              huv[k] = f2bf(b2f(hv[k]) * ug);
            }
            *(u16x8*)(ug_out + gidx) = ugv;
            *(u16x8*)(hu_out + gidx) = huv;
          }
        }
      } else {
#pragma unroll
        for (int s = 0; s < 8; ++s) {
          const int lc = tc * 4 + s * 32;
          const int gcol = col0 + lc;
          if (gcol < 896) {
            const f32x4 xa = *(const f32x4*)&xbuf[tr * 276 + lc];
            f32x4 o;
#pragma unroll
            for (int k = 0; k < 4; ++k)
              o[k] = 0.5f * xa[k] * (1.f + erff(xa[k] * 0.70710678118654752f));
            *(f32x4*)(fout + (size_t)grow * D + gcol) = o;
          }
        }
      }
      __syncthreads();
    }
  }
}

// ================== PLAN B (fallback, ws too small): R4 path ================

__device__ __forceinline__ void stage_f32_f(const float* __restrict__ g, int ld,
                                            int row0, int col0,
                                            unsigned short* lds, int tid) {
#pragma unroll
  for (int i = 0; i < 4; ++i) {
    const int idx = i * 256 + tid;
    const int r = idx >> 3, c8 = (idx & 7) * 8;
    const f32x8 v = *(const f32x8*)(g + (size_t)(row0 + r) * ld + (col0 + c8));
    u16x8 o;
#pragma unroll
    for (int k = 0; k < 8; ++k) o[k] = f2bf(v[k]);
    *(u16x8*)(lds + r * 64 + c8) = o;
  }
}
__device__ __forceinline__ void stage_att_f(const float* __restrict__ u_t,
                                            const float* __restrict__ logit,
                                            int row0, int col0,
                                            unsigned short* lds, int tid) {
#pragma unroll
  for (int i = 0; i < 4; ++i) {
    const int idx = i * 256 + tid;
    const int r = idx >> 3, c8 = (idx & 7) * 8;
    const float a = sigmoidf_(logit[row0 + r] * INV_SQRT_D);
    const f32x8 v = *(const f32x8*)(u_t + (size_t)(row0 + r) * D + (col0 + c8));
    u16x8 o;
#pragma unroll
    for (int k = 0; k < 8; ++k) o[k] = f2bf(v[k] * a);
    *(u16x8*)(lds + r * 64 + c8) = o;
  }
}
__device__ __forceinline__ void stage_bf16_f(const unsigned short* __restrict__ g,
                                             int row0, int col0,
                                             unsigned short* lds, int tid) {
#pragma unroll
  for (int i = 0; i < 4; ++i) {
    const int idx = i * 256 + tid;
    const int r = idx >> 3, c8 = (idx & 7) * 8;
    *(u16x8*)(lds + r * 64 + c8) =
        *(const u16x8*)(g + (size_t)(row0 + r) * D + (col0 + c8));
  }
}
__device__ __forceinline__ void stage_mul_f(const float* __restrict__ h,
                                            const unsigned short* __restrict__ ug,
                                            int row0, int col0,
                                            unsigned short* lds, int tid) {
#pragma unroll
  for (int i = 0; i < 4; ++i) {
    const int idx = i * 256 + tid;
    const int r = idx >> 3, c8 = (idx & 7) * 8;
    const size_t off = (size_t)(row0 + r) * D + (col0 + c8);
    const f32x8 vh = *(const f32x8*)(h + off);
    const u16x8 vu = *(const u16x8*)(ug + off);
    u16x8 o;
#pragma unroll
    for (int k = 0; k < 8; ++k) o[k] = f2bf(vh[k] * b2f(vu[k]));
    *(u16x8*)(lds + r * 64 + c8) = o;
  }
}

template <int MODE, int KITERS>
__global__ __launch_bounds__(256) void gemm_f(
    const float* __restrict__ A0, const float* __restrict__ A1,
    const unsigned short* __restrict__ Ab, const float* __restrict__ W, int ldw,
    const float* __restrict__ bias, float* __restrict__ logit,
    unsigned short* __restrict__ ug_out, float* __restrict__ fout) {
  __shared__ unsigned short sA[128 * 64];
  __shared__ unsigned short sB[128 * 64];
  const int tid = threadIdx.x;
  const int w = tid >> 6, l = tid & 63;
  const int quad = l >> 4, lane16 = l & 15;
  const int wrow = (w >> 1) * 64, wcol = (w & 1) * 64;
  const int row0 = (blockIdx.x & 127) * 128;
  const int col0 = (blockIdx.x >> 7) * 128;

  f32x4 acc[4][4];
#pragma unroll
  for (int i = 0; i < 4; ++i)
#pragma unroll
    for (int j = 0; j < 4; ++j) acc[i][j] = f32x4{0.f, 0.f, 0.f, 0.f};

  for (int kt = 0; kt < KITERS; ++kt) {
    const int k0 = kt * 64;
    if constexpr (MODE == 0) {
      stage_f32_f(A0, D, row0, k0, sA, tid);
    } else if constexpr (MODE == 1) {
      if (k0 < 896) stage_f32_f(A0, D, row0, k0, sA, tid);
      else stage_att_f(A1, logit, row0, k0 - 896, sA, tid);
    } else {
      if (k0 < 896) stage_f32_f(A0, D, row0, k0, sA, tid);
      else if (k0 < 1792) stage_bf16_f(Ab, row0, k0 - 896, sA, tid);
      else stage_mul_f(A0, Ab, row0, k0 - 1792, sA, tid);
    }
    stage_f32_f(W, ldw, col0, k0, sB, tid);
    __syncthreads();
#pragma unroll
    for (int ks = 0; ks < 2; ++ks) {
      bf16x8 fa[4], fb[4];
#pragma unroll
      for (int t = 0; t < 4; ++t) {
        fa[t] = ld8(sA + (wrow + t * 16 + lane16) * 64 + ks * 32 + quad * 8);
        fb[t] = ld8(sB + (wcol + t * 16 + lane16) * 64 + ks * 32 + quad * 8);
      }
#pragma unroll
      for (int i = 0; i < 4; ++i)
#pragma unroll
        for (int j = 0; j < 4; ++j)
          acc[i][j] = __builtin_amdgcn_mfma_f32_16x16x32_bf16(fa[i], fb[j], acc[i][j], 0, 0, 0);
    }
    __syncthreads();
  }

  float bj[4];
#pragma unroll
  for (int j = 0; j < 4; ++j) bj[j] = bias[col0 + wcol + j * 16 + lane16];

  if constexpr (MODE == 0) {
#pragma unroll
    for (int i = 0; i < 4; ++i) {
#pragma unroll
      for (int r = 0; r < 4; ++r) {
        const int row = row0 + wrow + i * 16 + quad * 4 + r;
        float s = 0.f;
#pragma unroll
        for (int j = 0; j < 4; ++j) {
          const int col = col0 + wcol + j * 16 + lane16;
          s += (acc[i][j][r] + bj[j]) * A1[(size_t)row * D + col];
        }
        s += __shfl_xor(s, 1, 64);
        s += __shfl_xor(s, 2, 64);
        s += __shfl_xor(s, 4, 64);
        s += __shfl_xor(s, 8, 64);
        if (lane16 == 0) atomicAdd(logit + row, s);
      }
    }
  } else {
#pragma unroll
    for (int i = 0; i < 4; ++i) {
#pragma unroll
      for (int r = 0; r < 4; ++r) {
        const int row = row0 + wrow + i * 16 + quad * 4 + r;
        float alpha;
        if constexpr (MODE == 1) alpha = sigmoidf_(logit[row] * INV_SQRT_D);
#pragma unroll
        for (int j = 0; j < 4; ++j) {
          const int col = col0 + wcol + j * 16 + lane16;
          const size_t idx = (size_t)row * D + col;
          const float x = acc[i][j][r] + bj[j];
          if constexpr (MODE == 1) {
            ug_out[idx] = f2bf(sigmoidf_(x) * alpha * A1[idx]);
          } else {
            fout[idx] = 0.5f * x * (1.f + erff(x * 0.70710678118654752f));
          }
        }
      }
    }
  }
}

// ============================================================================

extern "C" void kernel_launch(void* const* d_in, const int* in_sizes, int n_in,
                              void* d_out, int out_size, void* d_ws, size_t ws_size,
                              hipStream_t stream) {
  const float* h_t = (const float*)d_in[0];
  const float* u_t = (const float*)d_in[1];
  const float* W_a_w = (const float*)d_in[4];
  const float* W_a_b = (const float*)d_in[5];
  const float* W_g_w = (const float*)d_in[6];
  const float* W_g_b = (const float*)d_in[7];
  const float* W_f_w = (const float*)d_in[8];
  const float* W_f_b = (const float*)d_in[9];
  float* out = (float*)d_out;

  // Plan A scratch layout (bytes). Weights UNPADDED: col-panel-3 stage reads
  // of rows 896..1023 spill into the next allocation (garbage -> masked cols):
  //   wa_bf  bf16[896*896]   @ 0          (spill -> wg_bf, ok)
  //   wg_bf  bf16[896*1792]  @ 1605632    (spill -> wf_bf, ok)
  //   wf_bf  bf16[896*2688]  @ 4816896    (spill -> h_bf, ok)
  //   h_bf   bf16[N*D]       @ 9633792
  //   u_bf   bf16[N*D]       @ 38993920   (stays RAW u; alpha fused in MODE1)
  //   ug_bf  bf16[N*D]       @ 68354048
  //   hu_bf  bf16[N*D]       @ 97714176   -> end 127074304
  //   logit  f32[16384]      -> d_out front (dead before MODE2 overwrites)
  const size_t NEED = 127074304;

  if (ws_size >= NEED) {
    char* ws = (char*)d_ws;
    unsigned short* wa_bf = (unsigned short*)ws;
    unsigned short* wg_bf = (unsigned short*)(ws + 1605632);
    unsigned short* wf_bf = (unsigned short*)(ws + 4816896);
    unsigned short* h_bf = (unsigned short*)(ws + 9633792);
    unsigned short* u_bf = (unsigned short*)(ws + 38993920);
    unsigned short* ug_bf = (unsigned short*)(ws + 68354048);
    unsigned short* hu_bf = (unsigned short*)(ws + 97714176);
    float* logit = (float*)d_out;

    prep_k<<<dim3(16696), dim3(256), 0, stream>>>(h_t, u_t, W_a_w, W_g_w, W_f_w,
                                                  h_bf, u_bf, wa_bf, wg_bf,
                                                  wf_bf, logit);
    gemm8<0, 14><<<dim3(256), dim3(512), 0, stream>>>(
        u_bf, nullptr, nullptr, wa_bf, 896, W_a_b, h_bf, logit, nullptr,
        nullptr, nullptr);
    gemm8<1, 28><<<dim3(256), dim3(512), 0, stream>>>(
        h_bf, u_bf, nullptr, wg_bf, 1792, W_g_b, nullptr, logit, ug_bf,
        hu_bf, nullptr);
    gemm8<2, 42><<<dim3(256), dim3(512), 0, stream>>>(
        h_bf, ug_bf, hu_bf, wf_bf, 2688, W_f_b, nullptr, nullptr, nullptr,
        nullptr, out);
  } else {
    // Fallback (proven R4 path): logit in d_out front, u_gate in u_all buffer.
    unsigned short* u_gate = (unsigned short*)d_in[3];
    float* logit = (float*)d_out;
    const dim3 blk(256);
    const dim3 grid(128 * 7);
    hipMemsetAsync(d_out, 0, NTOK * sizeof(float), stream);
    gemm_f<0, 14><<<grid, blk, 0, stream>>>(u_t, h_t, nullptr, W_a_w, 896, W_a_b,
                                            logit, nullptr, nullptr);
    gemm_f<1, 28><<<grid, blk, 0, stream>>>(h_t, u_t, nullptr, W_g_w, 1792, W_g_b,
                                            logit, u_gate, nullptr);
    gemm_f<2, 42><<<grid, blk, 0, stream>>>(h_t, nullptr, u_gate, W_f_w, 2688,
                                            W_f_b, nullptr, nullptr, out);
  }
}